// Round 12
// baseline (475.479 us; speedup 1.0000x reference)
//
#include <hip/hip_runtime.h>
#include <hip/hip_bf16.h>
#include <math.h>

typedef __attribute__((ext_vector_type(8))) short bf16x8;
typedef __attribute__((ext_vector_type(8))) unsigned short u16x8;
typedef __attribute__((ext_vector_type(4))) float f32x4;
typedef __attribute__((ext_vector_type(4))) unsigned short u16x4;

__device__ inline unsigned short f2bf(float f) {
    union { float f; unsigned u; } v; v.f = f;
    unsigned r = (v.u + 0x7fff + ((v.u >> 16) & 1)) >> 16;   // RNE
    return (unsigned short)r;
}
__device__ inline float bf2f(unsigned short u) {
    union { unsigned u; float f; } v; v.u = ((unsigned)u) << 16; return v.f;
}

#define GLL16(gp, lp) __builtin_amdgcn_global_load_lds(                      \
    (const __attribute__((address_space(1))) void*)(gp),                     \
    (__attribute__((address_space(3))) void*)(lp), 16, 0, 0)

// ---------------------------------------------------------------------------
// bf16 MFMA GEMM, 2-phase stage-early double-buffered, BM templated:
// BM x 256 tile, BK=32, 8 waves (2x4), per-wave (BM/2) x 64 frags.
// Loop: STAGE(t+1 -> buf^1) issued BEFORE ds_read+MFMA of buf (HBM latency
// hides under compute); ONE __syncthreads per tile (drains vmcnt there).
// LDS: BM=256 -> 64KB dbuf (2 blocks/CU); BM=128 -> 48KB (3 blocks/CU).
// Swizzle involution (c^r^(r>>2))&3 on stage source + read slot; residual
// 2-way aliasing of 64B rows is free (m136, r10 A/B).
// EPI: 0=none 1=+bias 2=+bias+gelu(tanh-approx). OUT_BF: bf16 output.
// ---------------------------------------------------------------------------
template<int EPI, int OUT_BF, int BM>
__global__ __launch_bounds__(512) void gemm2ph(
    const unsigned short* __restrict__ A,
    const unsigned short* __restrict__ Bt,
    const float* __restrict__ bias,
    void* __restrict__ Cout,
    int M, int Nn, int K, int ldc)
{
    constexpr int ROWS = BM + 256;              // A rows ++ B rows
    constexpr int NL   = ROWS / 128;            // gloads/thread (3 or 4)
    constexpr int ABYT = BM * 64;               // A region bytes per buf
    constexpr int MI   = BM / 32;               // A frags per wave (4 or 8)
    __shared__ unsigned char lds[2][ROWS * 64];
    const int tid = threadIdx.x;
    const int w = tid >> 6, lane = tid & 63;
    const int lk = lane & 15, lg = lane >> 4;
    const int wr = w >> 2, wc = w & 3;          // 2 x 4 wave grid
    const int nbn = Nn >> 8;
    const int nb = gridDim.x;
    int bid = blockIdx.x;
    int swz = (nb & 7) ? bid : (bid & 7) * (nb >> 3) + (bid >> 3);  // XCD swizzle
    const int bm = (swz / nbn) * BM, bn = (swz % nbn) << 8;

    f32x4 acc[MI][4] = {};

    auto stage = [&](int buf, int k0) {
        #pragma unroll
        for (int i = 0; i < NL; ++i) {
            int s = tid + i * 512;
            int r = s >> 2, c = s & 3;
            int cs = (c ^ r ^ (r >> 2)) & 3;
            const unsigned short* gp = (r < BM)
                ? A  + (size_t)(bm + r) * K + k0 + cs * 8
                : Bt + (size_t)(bn + (r - BM)) * K + k0 + cs * 8;
            GLL16(gp, &lds[buf][s * 16]);
        }
    };

    const int NT = K >> 5;
    stage(0, 0);
    __syncthreads();                            // prologue drain
    int cur = 0;
    for (int t = 0; t < NT; ++t) {
        if (t + 1 < NT) stage(cur ^ 1, (t + 1) << 5);   // issue-early prefetch
        bf16x8 af[MI], bfr[4];
        #pragma unroll
        for (int mi = 0; mi < MI; ++mi) {
            int row = wr * (BM / 2) + mi * 16 + lk;
            int sl = (lg ^ row ^ (row >> 2)) & 3;
            af[mi] = *(const bf16x8*)&lds[cur][row * 64 + sl * 16];
        }
        #pragma unroll
        for (int nj = 0; nj < 4; ++nj) {
            int row = wc * 64 + nj * 16 + lk;
            int sl = (lg ^ row ^ (row >> 2)) & 3;
            bfr[nj] = *(const bf16x8*)&lds[cur][ABYT + row * 64 + sl * 16];
        }
        #pragma unroll
        for (int mi = 0; mi < MI; ++mi)
            #pragma unroll
            for (int nj = 0; nj < 4; ++nj)
                acc[mi][nj] = __builtin_amdgcn_mfma_f32_16x16x32_bf16(af[mi], bfr[nj], acc[mi][nj], 0, 0, 0);
        __syncthreads();                        // buf^1 staged, cur free
        cur ^= 1;
    }

    #pragma unroll
    for (int mi = 0; mi < MI; ++mi) {
        int row = bm + wr * (BM / 2) + mi * 16 + lg * 4;
        #pragma unroll
        for (int nj = 0; nj < 4; ++nj) {
            int col = bn + wc * 64 + nj * 16 + lk;
            #pragma unroll
            for (int r = 0; r < 4; ++r) {
                float v = acc[mi][nj][r];
                if (EPI >= 1) v += bias[col];
                if (EPI == 2) {
                    float u = v * 0.7978845608f * (1.0f + 0.044715f * v * v);
                    v = v / (1.0f + __expf(-2.0f * u));
                }
                if (OUT_BF)
                    ((unsigned short*)Cout)[(size_t)(row + r) * ldc + col] = f2bf(v);
                else
                    ((float*)Cout)[(size_t)(row + r) * ldc + col] = v;
            }
        }
    }
}

// ---------------------------------------------------------------------------
__global__ __launch_bounds__(256) void cvt_bf16(
    const float* __restrict__ src, unsigned short* __restrict__ dst, int n)
{
    int i = (blockIdx.x * 256 + threadIdx.x) * 4;
    if (i < n) {
        float4 v = *(const float4*)(src + i);
        u16x4 o = { f2bf(v.x), f2bf(v.y), f2bf(v.z), f2bf(v.w) };
        *(u16x4*)(dst + i) = o;
    }
}

// ---------------------------------------------------------------------------
__global__ __launch_bounds__(256) void transpose_cvt(
    const float* __restrict__ src, unsigned short* __restrict__ dst, int R, int Cc)
{
    __shared__ float t[32][33];
    const int bc = blockIdx.x * 32, br = blockIdx.y * 32;
    const int tx = threadIdx.x & 31, ty = threadIdx.x >> 5;
    #pragma unroll
    for (int i = 0; i < 4; ++i)
        t[ty + i * 8][tx] = src[(size_t)(br + ty + i * 8) * Cc + bc + tx];
    __syncthreads();
    #pragma unroll
    for (int i = 0; i < 4; ++i)
        dst[(size_t)(bc + ty + i * 8) * R + br + tx] = f2bf(t[tx][ty + i * 8]);
}

// ---------------------------------------------------------------------------
__global__ __launch_bounds__(256) void drofe_bf(
    const unsigned short* __restrict__ QK, unsigned short* __restrict__ Qo,
    unsigned short* __restrict__ Ko,
    const float* __restrict__ freqband, const float* __restrict__ demo, int N)
{
    const float PI_F = 3.14159265358979323846f;
    int idx = blockIdx.x * 256 + threadIdx.x;
    int col2 = idx & 511;
    int row  = idx >> 9;
    int n = row & (N - 1), b = row >> 10;
    int i  = col2 & 31;
    int ii = (i < 16) ? i : i - 16;
    float fb = (i < 16) ? freqband[n * 2 + 0] : freqband[n * 2 + 1];
    float freq = (1.0f + (float)ii * (4.0f / 15.0f)) * PI_F;
    float ang = fb * freq;
    float cv = cosf(ang), sv = sinf(ang);
    float ca = cv * demo[b * 2 + 0];
    float sg = sv * demo[b * 2 + 1];
    const unsigned* qk = (const unsigned*)(QK + (size_t)row * 2048);
    unsigned qu = qk[col2], ku = qk[512 + col2];
    float qe = bf2f((unsigned short)qu), qo_ = bf2f((unsigned short)(qu >> 16));
    float ke = bf2f((unsigned short)ku), ko_ = bf2f((unsigned short)(ku >> 16));
    const float s8 = 0.125f;
    unsigned qres = (unsigned)f2bf((qe * ca - qo_ * sg) * s8)
                  | ((unsigned)f2bf((qo_ * ca + qe * sg) * s8) << 16);
    unsigned kres = (unsigned)f2bf(ke * ca - ko_ * sg)
                  | ((unsigned)f2bf(ko_ * ca + ke * sg) << 16);
    ((unsigned*)Qo)[(size_t)row * 512 + col2] = qres;
    ((unsigned*)Ko)[(size_t)row * 512 + col2] = kres;
}

// ---------------------------------------------------------------------------
// Flash attention, bf16 in/out, MFMA 16x16x32, fp32 accum.
// r12: T14 async-STAGE split + double-buffered K/V (43KB LDS, 3 blocks/CU):
// issue K global_load_lds(t+1) + V global loads(t+1)->regs BEFORE computing
// tile t; V ds_write lands after the post-compute barrier (write-late).
// ---------------------------------------------------------------------------
__global__ __launch_bounds__(256) void attn_mfma(
    const unsigned short* __restrict__ Q, const unsigned short* __restrict__ K,
    const unsigned short* __restrict__ V, unsigned short* __restrict__ O,
    int B, int H, int N)
{
    __shared__ unsigned short Ks[2][64 * 64];
    __shared__ unsigned short Vt[2][64 * 72];
    __shared__ unsigned short Ps[4][16 * 72];

    const int bi = blockIdx.x;
    const int bh = (bi & 7) + 8 * ((bi >> 3) & 15);
    const int q0 = (bi >> 7) * 64;
    const int b = bh >> 4, h = bh & 15;
    const int tid = threadIdx.x;
    const int w = tid >> 6, lane = tid & 63;
    const int lg = lane >> 4, lk = lane & 15;
    const int vc = tid >> 5, vk0 = (tid & 31) * 2;

    bf16x8 qf[2];
    {
        const unsigned short* qrow = Q + (size_t)(b * N + q0 + w * 16 + lk) * 1024 + h * 64;
        qf[0] = *(const bf16x8*)(qrow + lg * 8);
        qf[1] = *(const bf16x8*)(qrow + 32 + lg * 8);
    }

    f32x4 o[4] = {};
    float mrow[4], lrow[4];
    #pragma unroll
    for (int r = 0; r < 4; ++r) { mrow[r] = -INFINITY; lrow[r] = 0.f; }

    auto issueK = [&](int buf, int t0) {
        const size_t kvbase = (size_t)(b * N + t0) * 1024 + h * 64;
        #pragma unroll
        for (int it = 0; it < 2; ++it) {
            int s = it * 256 + tid;
            int row = s >> 3, cb = (s & 7) << 4;
            int dby = cb ^ ((row & 7) << 4);
            GLL16(K + kvbase + (size_t)row * 1024 + (dby >> 1), &Ks[buf][s * 8]);
        }
    };
    auto loadV = [&](int t0, u16x8& va, u16x8& vb) {
        const unsigned short* vp = V + (size_t)(b * N + t0 + vk0) * 1024 + h * 64 + vc * 8;
        va = *(const u16x8*)vp;
        vb = *(const u16x8*)(vp + 1024);
    };
    auto writeV = [&](int buf, u16x8 va, u16x8 vb) {
        #pragma unroll
        for (int j = 0; j < 8; ++j) {
            unsigned val = (unsigned)va[j] | ((unsigned)vb[j] << 16);
            *(unsigned*)&Vt[buf][(vc * 8 + j) * 72 + vk0] = val;
        }
    };

    // prologue: tile 0 staged serially
    issueK(0, 0);
    { u16x8 va0, vb0; loadV(0, va0, vb0); writeV(0, va0, vb0); }
    __syncthreads();

    int cur = 0;
    for (int t0 = 0; t0 < N; t0 += 64) {
        u16x8 va, vb;
        const bool pre = (t0 + 64) < N;
        if (pre) { issueK(cur ^ 1, t0 + 64); loadV(t0 + 64, va, vb); }

        // S = Q K^T from Ks[cur]
        f32x4 s4[4];
        #pragma unroll
        for (int sub = 0; sub < 4; ++sub) {
            f32x4 acc = {0.f, 0.f, 0.f, 0.f};
            #pragma unroll
            for (int kh = 0; kh < 2; ++kh) {
                int cc = (kh * 64 + lg * 16) ^ ((lk & 7) << 4);
                bf16x8 kf = *(const bf16x8*)&Ks[cur][(sub * 16 + lk) * 64 + (cc >> 1)];
                acc = __builtin_amdgcn_mfma_f32_16x16x32_bf16(qf[kh], kf, acc, 0, 0, 0);
            }
            s4[sub] = acc;
        }

        // online softmax -> Ps (swizzled, trunc-cast)
        #pragma unroll
        for (int r = 0; r < 4; ++r) {
            float tm = fmaxf(fmaxf(s4[0][r], s4[1][r]), fmaxf(s4[2][r], s4[3][r]));
            #pragma unroll
            for (int msk = 1; msk < 16; msk <<= 1) tm = fmaxf(tm, __shfl_xor(tm, msk));
            float mn = fmaxf(mrow[r], tm);
            float corr = __expf(mrow[r] - mn);
            mrow[r] = mn;
            float psum = 0.f;
            unsigned short pb[4];
            #pragma unroll
            for (int sub = 0; sub < 4; ++sub) {
                float p = __expf(s4[sub][r] - mn);
                psum += p;
                pb[sub] = (unsigned short)(__float_as_uint(p) >> 16);
            }
            #pragma unroll
            for (int msk = 1; msk < 16; msk <<= 1) psum += __shfl_xor(psum, msk);
            lrow[r] = lrow[r] * corr + psum;
            #pragma unroll
            for (int ds = 0; ds < 4; ++ds) o[ds][r] *= corr;
            int q = lg * 4 + r;
            #pragma unroll
            for (int sub = 0; sub < 4; ++sub)
                Ps[w][q * 72 + (((sub * 16 + lk) ^ ((q >> 2) << 3)))] = pb[sub];
        }
        asm volatile("s_waitcnt lgkmcnt(0)" ::: "memory");   // per-wave P RAW

        // O += P V from Vt[cur]
        #pragma unroll
        for (int kh = 0; kh < 2; ++kh) {
            bf16x8 pf = *(const bf16x8*)&Ps[w][lk * 72 + ((kh * 32 + lg * 8) ^ ((lk >> 2) << 3))];
            #pragma unroll
            for (int ds = 0; ds < 4; ++ds) {
                bf16x8 vf = *(const bf16x8*)&Vt[cur][(ds * 16 + lk) * 72 + kh * 32 + lg * 8];
                o[ds] = __builtin_amdgcn_mfma_f32_16x16x32_bf16(pf, vf, o[ds], 0, 0, 0);
            }
        }
        __syncthreads();                 // done reading cur; prefetch landed
        if (pre) writeV(cur ^ 1, va, vb);
        __syncthreads();                 // Vt[cur^1] visible for next tile
        cur ^= 1;
    }

    #pragma unroll
    for (int ds = 0; ds < 4; ++ds)
        #pragma unroll
        for (int r = 0; r < 4; ++r) {
            int q = lg * 4 + r;
            O[(size_t)(b * N + q0 + w * 16 + q) * 1024 + h * 64 + ds * 16 + lk] =
                f2bf(o[ds][r] / lrow[r]);
        }
}

// ---------------------------------------------------------------------------
__global__ __launch_bounds__(256) void ln_res_kernel(
    const float* __restrict__ x, const float* __restrict__ y,
    const float* __restrict__ gamma, const float* __restrict__ w,
    const float* __restrict__ bia, float* __restrict__ out,
    unsigned short* __restrict__ out_bf, int C)
{
    const int row = blockIdx.x;
    __shared__ float buf[1024];
    __shared__ float red[8];
    const size_t base = (size_t)row * C;
    float s = 0.f, ss = 0.f;
    for (int c = threadIdx.x; c < C; c += 256) {
        float v = x[base + c] + gamma[c] * y[base + c];
        buf[c] = v; s += v; ss += v * v;
    }
    #pragma unroll
    for (int msk = 1; msk < 64; msk <<= 1) { s += __shfl_xor(s, msk); ss += __shfl_xor(ss, msk); }
    int wv = threadIdx.x >> 6, lane = threadIdx.x & 63;
    if (lane == 0) { red[wv * 2] = s; red[wv * 2 + 1] = ss; }
    __syncthreads();
    if (threadIdx.x == 0) {
        float S = 0.f, SS = 0.f;
        #pragma unroll
        for (int i = 0; i < 4; ++i) { S += red[2 * i]; SS += red[2 * i + 1]; }
        red[0] = S; red[1] = SS;
    }
    __syncthreads();
    float mu = red[0] / C;
    float var = red[1] / C - mu * mu;
    float rstd = rsqrtf(var + 1e-5f);
    for (int c = threadIdx.x; c < C; c += 256) {
        float v = (buf[c] - mu) * rstd * w[c] + bia[c];
        out[base + c] = v;
        if (out_bf) out_bf[base + c] = f2bf(v);
    }
}

// ---------------------------------------------------------------------------
extern "C" void kernel_launch(void* const* d_in, const int* in_sizes, int n_in,
                              void* d_out, int out_size, void* d_ws, size_t ws_size,
                              hipStream_t stream)
{
    const float* x      = (const float*)d_in[0];
    const float* demo   = (const float*)d_in[1];
    const float* expl   = (const float*)d_in[2];
    const float* fb     = (const float*)d_in[3];
    const float* w_qkv  = (const float*)d_in[4];
    const float* w_proj = (const float*)d_in[5];
    const float* b_proj = (const float*)d_in[6];
    const float* gamma1 = (const float*)d_in[7];
    const float* gamma2 = (const float*)d_in[8];
    const float* ln1_w  = (const float*)d_in[9];
    const float* ln1_b  = (const float*)d_in[10];
    const float* ln2_w  = (const float*)d_in[11];
    const float* ln2_b  = (const float*)d_in[12];
    const float* w1     = (const float*)d_in[13];
    const float* b1     = (const float*)d_in[14];
    const float* w2     = (const float*)d_in[15];
    const float* b2     = (const float*)d_in[16];
    float* out = (float*)d_out;

    const int B = 8, N = 1024, C = 1024, F = 4096, H = 16;
    const int M = B * N;                        // 8192
    const size_t Mi = 1048576;

    float* ws = (float*)d_ws;
    unsigned short* QKbf = (unsigned short*)ws;              // M x 2048 bf16
    unsigned short* Obf  = (unsigned short*)ws;              // M x 1024 bf16
    float*          H2   = ws;                               // M x 1024 f32
    unsigned short* Qbf  = (unsigned short*)(ws + 8 * Mi);   // M x 1024 bf16
    unsigned short* Kbf  = (unsigned short*)(ws + 12 * Mi);
    unsigned short* Vbf  = (unsigned short*)(ws + 16 * Mi);
    unsigned short* Hid  = (unsigned short*)(ws + 8 * Mi);   // M x 4096 bf16
    unsigned short* Ebf  = (unsigned short*)(ws + 24 * Mi);
    unsigned short* Xbf  = (unsigned short*)(ws + 28 * Mi);
    float*          Pb   = ws + 24 * Mi;                     // M x 1024 f32
    float*          X1   = ws + 32 * Mi;                     // M x 1024 f32
    unsigned short* X1bf = (unsigned short*)(ws + 40 * Mi);
    unsigned short* Wt   = (unsigned short*)(ws + 44 * Mi);
    unsigned short* wqkvT  = Wt;                             // [3072][1024]
    unsigned short* wprojT = Wt + (size_t)3145728;           // [1024][1024]
    unsigned short* w1T    = wprojT + (size_t)1048576;       // [4096][1024]
    unsigned short* w2T    = w1T + (size_t)4194304;          // [1024][4096]

    dim3 blk(256);
    dim3 blk5(512);
    const int MC = M * C;

    hipLaunchKernelGGL(cvt_bf16, dim3(MC / 1024), blk, 0, stream, expl, Ebf, MC);
    hipLaunchKernelGGL(cvt_bf16, dim3(MC / 1024), blk, 0, stream, x, Xbf, MC);
    hipLaunchKernelGGL(transpose_cvt, dim3(96, 32), blk, 0, stream, w_qkv, wqkvT, C, 3 * C);
    hipLaunchKernelGGL(transpose_cvt, dim3(32, 32), blk, 0, stream, w_proj, wprojT, C, C);
    hipLaunchKernelGGL(transpose_cvt, dim3(128, 32), blk, 0, stream, w1, w1T, C, F);
    hipLaunchKernelGGL(transpose_cvt, dim3(32, 128), blk, 0, stream, w2, w2T, F, C);

    // QK projection [2ph 256x256]; V projection [2ph 128x256]
    hipLaunchKernelGGL((gemm2ph<0,1,256>), dim3(32 * 8), blk5, 0, stream, Ebf, wqkvT, (const float*)nullptr, (void*)QKbf, M, 2048, C, 2048);
    hipLaunchKernelGGL((gemm2ph<0,1,128>), dim3(64 * 4), blk5, 0, stream, Xbf, wqkvT + (size_t)2048 * 1024, (const float*)nullptr, (void*)Vbf, M, 1024, C, 1024);

    // drofe: bf16 QK -> rotated bf16 Q (scaled), K
    hipLaunchKernelGGL(drofe_bf, dim3(M * 512 / 256), blk, 0, stream, QKbf, Qbf, Kbf, fb, demo, N);

    // attention -> bf16 O
    hipLaunchKernelGGL(attn_mfma, dim3(B * H * (N / 64)), blk, 0, stream, Qbf, Kbf, Vbf, Obf, B, H, N);

    // output projection [2ph 128x256]
    hipLaunchKernelGGL((gemm2ph<1,0,128>), dim3(64 * 4), blk5, 0, stream, Obf, wprojT, b_proj, (void*)Pb, M, 1024, C, 1024);

    // residual + LN1 (f32 + bf16)
    hipLaunchKernelGGL(ln_res_kernel, dim3(M), blk, 0, stream, x, Pb, gamma1, ln1_w, ln1_b, X1, X1bf, C);

    // MLP: MLP1 [2ph 256x256, fast gelu], MLP2 [2ph 128x256, K=4096]
    hipLaunchKernelGGL((gemm2ph<2,1,256>), dim3(32 * 16), blk5, 0, stream, X1bf, w1T, b1, (void*)Hid, M, F, C, F);
    hipLaunchKernelGGL((gemm2ph<1,0,128>), dim3(64 * 4), blk5, 0, stream, Hid, w2T, b2, (void*)H2, M, 1024, F, 1024);

    // residual + LN2 -> out
    hipLaunchKernelGGL(ln_res_kernel, dim3(M), blk, 0, stream, X1, H2, gamma2, ln2_w, ln2_b, out, (unsigned short*)nullptr, C);
}

// Round 13
// 475.305 us; speedup vs baseline: 1.0004x; 1.0004x over previous
//
#include <hip/hip_runtime.h>
#include <hip/hip_bf16.h>
#include <math.h>

typedef __attribute__((ext_vector_type(8))) short bf16x8;
typedef __attribute__((ext_vector_type(8))) unsigned short u16x8;
typedef __attribute__((ext_vector_type(4))) float f32x4;
typedef __attribute__((ext_vector_type(4))) unsigned short u16x4;

__device__ inline unsigned short f2bf(float f) {
    union { float f; unsigned u; } v; v.f = f;
    unsigned r = (v.u + 0x7fff + ((v.u >> 16) & 1)) >> 16;   // RNE
    return (unsigned short)r;
}
__device__ inline float bf2f(unsigned short u) {
    union { unsigned u; float f; } v; v.u = ((unsigned)u) << 16; return v.f;
}

#define GLL16(gp, lp) __builtin_amdgcn_global_load_lds(                      \
    (const __attribute__((address_space(1))) void*)(gp),                     \
    (__attribute__((address_space(3))) void*)(lp), 16, 0, 0)

// ---------------------------------------------------------------------------
// bf16 MFMA GEMM, 2-phase stage-early double-buffered (r11-verified):
// 256x256 tile, BK=32, 8 waves (2x4). STAGE(t+1) issued before compute(t);
// one __syncthreads per tile. 64KB dbuf LDS.
// ---------------------------------------------------------------------------
template<int EPI, int OUT_BF>
__global__ __launch_bounds__(512) void gemm2ph(
    const unsigned short* __restrict__ A,
    const unsigned short* __restrict__ Bt,
    const float* __restrict__ bias,
    void* __restrict__ Cout,
    int M, int Nn, int K, int ldc)
{
    __shared__ unsigned char lds[2][32768];
    const int tid = threadIdx.x;
    const int w = tid >> 6, lane = tid & 63;
    const int lk = lane & 15, lg = lane >> 4;
    const int wr = w >> 2, wc = w & 3;
    const int nbn = Nn >> 8;
    const int nb = gridDim.x;
    int bid = blockIdx.x;
    int swz = (nb & 7) ? bid : (bid & 7) * (nb >> 3) + (bid >> 3);
    const int bm = (swz / nbn) << 8, bn = (swz % nbn) << 8;

    f32x4 acc[8][4] = {};

    auto stage = [&](int buf, int k0) {
        #pragma unroll
        for (int i = 0; i < 4; ++i) {
            int s = tid + i * 512;
            int r = s >> 2, c = s & 3;
            int cs = (c ^ r ^ (r >> 2)) & 3;
            const unsigned short* gp = (r < 256)
                ? A  + (size_t)(bm + r) * K + k0 + cs * 8
                : Bt + (size_t)(bn + (r - 256)) * K + k0 + cs * 8;
            GLL16(gp, &lds[buf][s * 16]);
        }
    };

    const int NT = K >> 5;
    stage(0, 0);
    __syncthreads();
    int cur = 0;
    for (int t = 0; t < NT; ++t) {
        if (t + 1 < NT) stage(cur ^ 1, (t + 1) << 5);
        bf16x8 af[8], bfr[4];
        #pragma unroll
        for (int mi = 0; mi < 8; ++mi) {
            int row = wr * 128 + mi * 16 + lk;
            int sl = (lg ^ row ^ (row >> 2)) & 3;
            af[mi] = *(const bf16x8*)&lds[cur][row * 64 + sl * 16];
        }
        #pragma unroll
        for (int nj = 0; nj < 4; ++nj) {
            int row = wc * 64 + nj * 16 + lk;
            int sl = (lg ^ row ^ (row >> 2)) & 3;
            bfr[nj] = *(const bf16x8*)&lds[cur][16384 + row * 64 + sl * 16];
        }
        #pragma unroll
        for (int mi = 0; mi < 8; ++mi)
            #pragma unroll
            for (int nj = 0; nj < 4; ++nj)
                acc[mi][nj] = __builtin_amdgcn_mfma_f32_16x16x32_bf16(af[mi], bfr[nj], acc[mi][nj], 0, 0, 0);
        __syncthreads();
        cur ^= 1;
    }

    #pragma unroll
    for (int mi = 0; mi < 8; ++mi) {
        int row = bm + wr * 128 + mi * 16 + lg * 4;
        #pragma unroll
        for (int nj = 0; nj < 4; ++nj) {
            int col = bn + wc * 64 + nj * 16 + lk;
            #pragma unroll
            for (int r = 0; r < 4; ++r) {
                float v = acc[mi][nj][r];
                if (EPI >= 1) v += bias[col];
                if (EPI == 2) {
                    float u = v * 0.7978845608f * (1.0f + 0.044715f * v * v);
                    v = v / (1.0f + __expf(-2.0f * u));
                }
                if (OUT_BF)
                    ((unsigned short*)Cout)[(size_t)(row + r) * ldc + col] = f2bf(v);
                else
                    ((float*)Cout)[(size_t)(row + r) * ldc + col] = v;
            }
        }
    }
}

// ---------------------------------------------------------------------------
// bf16 MFMA GEMM, m97 structure, templated BK (r7/r10-verified).
// ---------------------------------------------------------------------------
template<int EPI, int OUT_BF, int BK>
__global__ __launch_bounds__(256) void gemm97(
    const unsigned short* __restrict__ A,
    const unsigned short* __restrict__ Bt,
    const float* __restrict__ bias,
    void* __restrict__ Cout,
    int M, int Nn, int K, int ldc)
{
    constexpr int SPR = BK / 8;
    constexpr int RB  = BK * 2;
    __shared__ unsigned char lds[256 * BK * 2];
    const int tid = threadIdx.x;
    const int w = tid >> 6, lane = tid & 63;
    const int lk = lane & 15, lg = lane >> 4;
    const int wr = w >> 1, wc = w & 1;
    const int nbn = Nn >> 7;
    const int nb = gridDim.x;
    int bid = blockIdx.x;
    int swz = (nb & 7) ? bid : (bid & 7) * (nb >> 3) + (bid >> 3);
    const int bm = (swz / nbn) << 7, bn = (swz % nbn) << 7;

    f32x4 acc[4][4] = {};

    for (int k0 = 0; k0 < K; k0 += BK) {
        #pragma unroll
        for (int i = 0; i < SPR; ++i) {
            int s = tid + i * 256;
            int r = s / SPR, c = s % SPR;
            int cs;
            if constexpr (SPR == 4) cs = (c ^ r ^ (r >> 2)) & 3;
            else                    cs = c ^ (r & 7);
            const unsigned short* gp = (r < 128)
                ? A  + (size_t)(bm + r) * K + k0 + cs * 8
                : Bt + (size_t)(bn + (r - 128)) * K + k0 + cs * 8;
            GLL16(gp, &lds[s * 16]);
        }
        __syncthreads();

        #pragma unroll
        for (int kk = 0; kk < BK / 32; ++kk) {
            bf16x8 af[4], bfr[4];
            #pragma unroll
            for (int m = 0; m < 4; ++m) {
                int row = wr * 64 + m * 16 + lk;
                int sl;
                if constexpr (SPR == 4) sl = ((kk * 4 + lg) ^ row ^ (row >> 2)) & 3;
                else                    sl = (kk * 4 + lg) ^ (row & 7);
                af[m] = *(const bf16x8*)&lds[row * RB + sl * 16];
            }
            #pragma unroll
            for (int n = 0; n < 4; ++n) {
                int row = wc * 64 + n * 16 + lk;
                int sl;
                if constexpr (SPR == 4) sl = ((kk * 4 + lg) ^ row ^ (row >> 2)) & 3;
                else                    sl = (kk * 4 + lg) ^ (row & 7);
                bfr[n] = *(const bf16x8*)&lds[128 * RB + row * RB + sl * 16];
            }
            #pragma unroll
            for (int m = 0; m < 4; ++m)
                #pragma unroll
                for (int n = 0; n < 4; ++n)
                    acc[m][n] = __builtin_amdgcn_mfma_f32_16x16x32_bf16(af[m], bfr[n], acc[m][n], 0, 0, 0);
        }
        __syncthreads();
    }

    #pragma unroll
    for (int m = 0; m < 4; ++m) {
        int row = bm + wr * 64 + m * 16 + lg * 4;
        #pragma unroll
        for (int n = 0; n < 4; ++n) {
            int col = bn + wc * 64 + n * 16 + lk;
            #pragma unroll
            for (int r = 0; r < 4; ++r) {
                float v = acc[m][n][r];
                if (EPI >= 1) v += bias[col];
                if (EPI == 2) {
                    float u = v * 0.7978845608f * (1.0f + 0.044715f * v * v);
                    v = v / (1.0f + __expf(-2.0f * u));
                }
                if (OUT_BF)
                    ((unsigned short*)Cout)[(size_t)(row + r) * ldc + col] = f2bf(v);
                else
                    ((float*)Cout)[(size_t)(row + r) * ldc + col] = v;
            }
        }
    }
}

// ---------------------------------------------------------------------------
__global__ __launch_bounds__(256) void cvt_bf16(
    const float* __restrict__ src, unsigned short* __restrict__ dst, int n)
{
    int i = (blockIdx.x * 256 + threadIdx.x) * 4;
    if (i < n) {
        float4 v = *(const float4*)(src + i);
        u16x4 o = { f2bf(v.x), f2bf(v.y), f2bf(v.z), f2bf(v.w) };
        *(u16x4*)(dst + i) = o;
    }
}

// ---------------------------------------------------------------------------
__global__ __launch_bounds__(256) void transpose_cvt(
    const float* __restrict__ src, unsigned short* __restrict__ dst, int R, int Cc)
{
    __shared__ float t[32][33];
    const int bc = blockIdx.x * 32, br = blockIdx.y * 32;
    const int tx = threadIdx.x & 31, ty = threadIdx.x >> 5;
    #pragma unroll
    for (int i = 0; i < 4; ++i)
        t[ty + i * 8][tx] = src[(size_t)(br + ty + i * 8) * Cc + bc + tx];
    __syncthreads();
    #pragma unroll
    for (int i = 0; i < 4; ++i)
        dst[(size_t)(bc + ty + i * 8) * R + br + tx] = f2bf(t[tx][ty + i * 8]);
}

// ---------------------------------------------------------------------------
__global__ __launch_bounds__(256) void drofe_bf(
    const unsigned short* __restrict__ QK, unsigned short* __restrict__ Qo,
    unsigned short* __restrict__ Ko,
    const float* __restrict__ freqband, const float* __restrict__ demo, int N)
{
    const float PI_F = 3.14159265358979323846f;
    int idx = blockIdx.x * 256 + threadIdx.x;
    int col2 = idx & 511;
    int row  = idx >> 9;
    int n = row & (N - 1), b = row >> 10;
    int i  = col2 & 31;
    int ii = (i < 16) ? i : i - 16;
    float fb = (i < 16) ? freqband[n * 2 + 0] : freqband[n * 2 + 1];
    float freq = (1.0f + (float)ii * (4.0f / 15.0f)) * PI_F;
    float ang = fb * freq;
    float cv = cosf(ang), sv = sinf(ang);
    float ca = cv * demo[b * 2 + 0];
    float sg = sv * demo[b * 2 + 1];
    const unsigned* qk = (const unsigned*)(QK + (size_t)row * 2048);
    unsigned qu = qk[col2], ku = qk[512 + col2];
    float qe = bf2f((unsigned short)qu), qo_ = bf2f((unsigned short)(qu >> 16));
    float ke = bf2f((unsigned short)ku), ko_ = bf2f((unsigned short)(ku >> 16));
    const float s8 = 0.125f;
    unsigned qres = (unsigned)f2bf((qe * ca - qo_ * sg) * s8)
                  | ((unsigned)f2bf((qo_ * ca + qe * sg) * s8) << 16);
    unsigned kres = (unsigned)f2bf(ke * ca - ko_ * sg)
                  | ((unsigned)f2bf(ko_ * ca + ke * sg) << 16);
    ((unsigned*)Qo)[(size_t)row * 512 + col2] = qres;
    ((unsigned*)Ko)[(size_t)row * 512 + col2] = kres;
}

// ---------------------------------------------------------------------------
// Flash attention, bf16 in/out, MFMA 16x16x32, fp32 accum.
// r13: Vt and Ps moved to the ZERO-CONFLICT pattern measured in gemm97-BK64
// (128B rows + slot-XOR (row&7) involution). The old stride-72 rows were
// 16B mod 128B -> rows lk,lk+8 shared bank quads -> 4-8 way b128 conflicts
// (the constant 5.2M counter). Single-buffered (r12 dbuf measured neutral).
// ---------------------------------------------------------------------------
__global__ __launch_bounds__(256) void attn_mfma(
    const unsigned short* __restrict__ Q, const unsigned short* __restrict__ K,
    const unsigned short* __restrict__ V, unsigned short* __restrict__ O,
    int B, int H, int N)
{
    __shared__ unsigned short Ks[64 * 64];
    __shared__ unsigned short Vt[64 * 64];
    __shared__ unsigned short Ps[4][16 * 64];

    const int bi = blockIdx.x;
    const int bh = (bi & 7) + 8 * ((bi >> 3) & 15);
    const int q0 = (bi >> 7) * 64;
    const int b = bh >> 4, h = bh & 15;
    const int tid = threadIdx.x;
    const int w = tid >> 6, lane = tid & 63;
    const int lg = lane >> 4, lk = lane & 15;

    bf16x8 qf[2];
    {
        const unsigned short* qrow = Q + (size_t)(b * N + q0 + w * 16 + lk) * 1024 + h * 64;
        qf[0] = *(const bf16x8*)(qrow + lg * 8);
        qf[1] = *(const bf16x8*)(qrow + 32 + lg * 8);
    }

    f32x4 o[4] = {};
    float mrow[4], lrow[4];
    #pragma unroll
    for (int r = 0; r < 4; ++r) { mrow[r] = -INFINITY; lrow[r] = 0.f; }

    for (int t0 = 0; t0 < N; t0 += 64) {
        const size_t kvbase = (size_t)(b * N + t0) * 1024 + h * 64;
        #pragma unroll
        for (int it = 0; it < 2; ++it) {        // K: swizzled-source GLL
            int s = it * 256 + tid;
            int row = s >> 3, cb = (s & 7) << 4;
            int dby = cb ^ ((row & 7) << 4);
            GLL16(K + kvbase + (size_t)row * 1024 + (dby >> 1), &Ks[s * 8]);
        }
        {                                       // V: reg-staged transpose, swizzled
            int c = tid >> 5, k0 = (tid & 31) * 2;
            const unsigned short* vp = V + kvbase + (size_t)k0 * 1024 + c * 8;
            u16x8 va = *(const u16x8*)vp;
            u16x8 vb = *(const u16x8*)(vp + 1024);
            #pragma unroll
            for (int j = 0; j < 8; ++j) {
                int row = c * 8 + j;            // d index
                unsigned val = (unsigned)va[j] | ((unsigned)vb[j] << 16);
                int sl = (k0 >> 3) ^ (row & 7);
                *(unsigned*)&Vt[row * 64 + sl * 8 + (k0 & 7)] = val;
            }
        }
        __syncthreads();

        f32x4 s4[4];
        #pragma unroll
        for (int sub = 0; sub < 4; ++sub) {
            f32x4 acc = {0.f, 0.f, 0.f, 0.f};
            #pragma unroll
            for (int kh = 0; kh < 2; ++kh) {
                int cc = (kh * 64 + lg * 16) ^ ((lk & 7) << 4);
                bf16x8 kf = *(const bf16x8*)&Ks[(sub * 16 + lk) * 64 + (cc >> 1)];
                acc = __builtin_amdgcn_mfma_f32_16x16x32_bf16(qf[kh], kf, acc, 0, 0, 0);
            }
            s4[sub] = acc;
        }

        #pragma unroll
        for (int r = 0; r < 4; ++r) {
            float tm = fmaxf(fmaxf(s4[0][r], s4[1][r]), fmaxf(s4[2][r], s4[3][r]));
            #pragma unroll
            for (int msk = 1; msk < 16; msk <<= 1) tm = fmaxf(tm, __shfl_xor(tm, msk));
            float mn = fmaxf(mrow[r], tm);
            float corr = __expf(mrow[r] - mn);
            mrow[r] = mn;
            float psum = 0.f;
            unsigned short pb[4];
            #pragma unroll
            for (int sub = 0; sub < 4; ++sub) {
                float p = __expf(s4[sub][r] - mn);
                psum += p;
                pb[sub] = (unsigned short)(__float_as_uint(p) >> 16);  // trunc
            }
            #pragma unroll
            for (int msk = 1; msk < 16; msk <<= 1) psum += __shfl_xor(psum, msk);
            lrow[r] = lrow[r] * corr + psum;
            #pragma unroll
            for (int ds = 0; ds < 4; ++ds) o[ds][r] *= corr;
            int q = lg * 4 + r;
            #pragma unroll
            for (int sub = 0; sub < 4; ++sub) {
                int col = sub * 16 + lk;
                int sl = (col >> 3) ^ (q & 7);
                Ps[w][q * 64 + sl * 8 + (col & 7)] = pb[sub];
            }
        }
        asm volatile("s_waitcnt lgkmcnt(0)" ::: "memory");

        #pragma unroll
        for (int kh = 0; kh < 2; ++kh) {
            bf16x8 pf = *(const bf16x8*)&Ps[w][lk * 64 + (((kh * 4 + lg) ^ (lk & 7)) << 3)];
            #pragma unroll
            for (int ds = 0; ds < 4; ++ds) {
                bf16x8 vf = *(const bf16x8*)&Vt[(ds * 16 + lk) * 64 + (((kh * 4 + lg) ^ (lk & 7)) << 3)];
                o[ds] = __builtin_amdgcn_mfma_f32_16x16x32_bf16(pf, vf, o[ds], 0, 0, 0);
            }
        }
        __syncthreads();
    }

    #pragma unroll
    for (int ds = 0; ds < 4; ++ds)
        #pragma unroll
        for (int r = 0; r < 4; ++r) {
            int q = lg * 4 + r;
            O[(size_t)(b * N + q0 + w * 16 + q) * 1024 + h * 64 + ds * 16 + lk] =
                f2bf(o[ds][r] / lrow[r]);
        }
}

// ---------------------------------------------------------------------------
__global__ __launch_bounds__(256) void ln_res_kernel(
    const float* __restrict__ x, const float* __restrict__ y,
    const float* __restrict__ gamma, const float* __restrict__ w,
    const float* __restrict__ bia, float* __restrict__ out,
    unsigned short* __restrict__ out_bf, int C)
{
    const int row = blockIdx.x;
    __shared__ float buf[1024];
    __shared__ float red[8];
    const size_t base = (size_t)row * C;
    float s = 0.f, ss = 0.f;
    for (int c = threadIdx.x; c < C; c += 256) {
        float v = x[base + c] + gamma[c] * y[base + c];
        buf[c] = v; s += v; ss += v * v;
    }
    #pragma unroll
    for (int msk = 1; msk < 64; msk <<= 1) { s += __shfl_xor(s, msk); ss += __shfl_xor(ss, msk); }
    int wv = threadIdx.x >> 6, lane = threadIdx.x & 63;
    if (lane == 0) { red[wv * 2] = s; red[wv * 2 + 1] = ss; }
    __syncthreads();
    if (threadIdx.x == 0) {
        float S = 0.f, SS = 0.f;
        #pragma unroll
        for (int i = 0; i < 4; ++i) { S += red[2 * i]; SS += red[2 * i + 1]; }
        red[0] = S; red[1] = SS;
    }
    __syncthreads();
    float mu = red[0] / C;
    float var = red[1] / C - mu * mu;
    float rstd = rsqrtf(var + 1e-5f);
    for (int c = threadIdx.x; c < C; c += 256) {
        float v = (buf[c] - mu) * rstd * w[c] + bia[c];
        out[base + c] = v;
        if (out_bf) out_bf[base + c] = f2bf(v);
    }
}

// ---------------------------------------------------------------------------
extern "C" void kernel_launch(void* const* d_in, const int* in_sizes, int n_in,
                              void* d_out, int out_size, void* d_ws, size_t ws_size,
                              hipStream_t stream)
{
    const float* x      = (const float*)d_in[0];
    const float* demo   = (const float*)d_in[1];
    const float* expl   = (const float*)d_in[2];
    const float* fb     = (const float*)d_in[3];
    const float* w_qkv  = (const float*)d_in[4];
    const float* w_proj = (const float*)d_in[5];
    const float* b_proj = (const float*)d_in[6];
    const float* gamma1 = (const float*)d_in[7];
    const float* gamma2 = (const float*)d_in[8];
    const float* ln1_w  = (const float*)d_in[9];
    const float* ln1_b  = (const float*)d_in[10];
    const float* ln2_w  = (const float*)d_in[11];
    const float* ln2_b  = (const float*)d_in[12];
    const float* w1     = (const float*)d_in[13];
    const float* b1     = (const float*)d_in[14];
    const float* w2     = (const float*)d_in[15];
    const float* b2     = (const float*)d_in[16];
    float* out = (float*)d_out;

    const int B = 8, N = 1024, C = 1024, F = 4096, H = 16;
    const int M = B * N;                        // 8192
    const size_t Mi = 1048576;

    float* ws = (float*)d_ws;
    unsigned short* QKbf = (unsigned short*)ws;              // M x 2048 bf16
    unsigned short* Obf  = (unsigned short*)ws;              // M x 1024 bf16
    float*          H2   = ws;                               // M x 1024 f32
    unsigned short* Qbf  = (unsigned short*)(ws + 8 * Mi);   // M x 1024 bf16
    unsigned short* Kbf  = (unsigned short*)(ws + 12 * Mi);
    unsigned short* Vbf  = (unsigned short*)(ws + 16 * Mi);
    unsigned short* Hid  = (unsigned short*)(ws + 8 * Mi);   // M x 4096 bf16
    unsigned short* Ebf  = (unsigned short*)(ws + 24 * Mi);
    unsigned short* Xbf  = (unsigned short*)(ws + 28 * Mi);
    float*          Pb   = ws + 24 * Mi;                     // M x 1024 f32
    float*          X1   = ws + 32 * Mi;                     // M x 1024 f32
    unsigned short* X1bf = (unsigned short*)(ws + 40 * Mi);
    unsigned short* Wt   = (unsigned short*)(ws + 44 * Mi);
    unsigned short* wqkvT  = Wt;                             // [3072][1024]
    unsigned short* wprojT = Wt + (size_t)3145728;           // [1024][1024]
    unsigned short* w1T    = wprojT + (size_t)1048576;       // [4096][1024]
    unsigned short* w2T    = w1T + (size_t)4194304;          // [1024][4096]

    dim3 blk(256);
    dim3 blk5(512);
    const int MC = M * C;

    hipLaunchKernelGGL(cvt_bf16, dim3(MC / 1024), blk, 0, stream, expl, Ebf, MC);
    hipLaunchKernelGGL(cvt_bf16, dim3(MC / 1024), blk, 0, stream, x, Xbf, MC);
    hipLaunchKernelGGL(transpose_cvt, dim3(96, 32), blk, 0, stream, w_qkv, wqkvT, C, 3 * C);
    hipLaunchKernelGGL(transpose_cvt, dim3(32, 32), blk, 0, stream, w_proj, wprojT, C, C);
    hipLaunchKernelGGL(transpose_cvt, dim3(128, 32), blk, 0, stream, w1, w1T, C, F);
    hipLaunchKernelGGL(transpose_cvt, dim3(32, 128), blk, 0, stream, w2, w2T, F, C);

    // QK projection [2ph 256^2]; V projection [gemm97 BK=32]
    hipLaunchKernelGGL((gemm2ph<0,1>), dim3(32 * 8), blk5, 0, stream, Ebf, wqkvT, (const float*)nullptr, (void*)QKbf, M, 2048, C, 2048);
    hipLaunchKernelGGL((gemm97<0,1,32>), dim3(64 * 8), blk, 0, stream, Xbf, wqkvT + (size_t)2048 * 1024, (const float*)nullptr, (void*)Vbf, M, 1024, C, 1024);

    // drofe: bf16 QK -> rotated bf16 Q (scaled), K
    hipLaunchKernelGGL(drofe_bf, dim3(M * 512 / 256), blk, 0, stream, QKbf, Qbf, Kbf, fb, demo, N);

    // attention -> bf16 O
    hipLaunchKernelGGL(attn_mfma, dim3(B * H * (N / 64)), blk, 0, stream, Qbf, Kbf, Vbf, Obf, B, H, N);

    // output projection [gemm97 BK=32]
    hipLaunchKernelGGL((gemm97<1,0,32>), dim3(64 * 8), blk, 0, stream, Obf, wprojT, b_proj, (void*)Pb, M, 1024, C, 1024);

    // residual + LN1 (f32 + bf16)
    hipLaunchKernelGGL(ln_res_kernel, dim3(M), blk, 0, stream, x, Pb, gamma1, ln1_w, ln1_b, X1, X1bf, C);

    // MLP: MLP1 [2ph 256^2, fast gelu], MLP2 [gemm97 BK=64]
    hipLaunchKernelGGL((gemm2ph<2,1>), dim3(32 * 16), blk5, 0, stream, X1bf, w1T, b1, (void*)Hid, M, F, C, F);
    hipLaunchKernelGGL((gemm97<1,0,64>), dim3(64 * 8), blk, 0, stream, Hid, w2T, b2, (void*)H2, M, 1024, F, 1024);

    // residual + LN2 -> out
    hipLaunchKernelGGL(ln_res_kernel, dim3(M), blk, 0, stream, X1, H2, gamma2, ln2_w, ln2_b, out, (unsigned short*)nullptr, C);
}

// Round 14
// 429.499 us; speedup vs baseline: 1.1071x; 1.1066x over previous
//
#include <hip/hip_runtime.h>
#include <hip/hip_bf16.h>
#include <math.h>

typedef __attribute__((ext_vector_type(8))) short bf16x8;
typedef __attribute__((ext_vector_type(8))) unsigned short u16x8;
typedef __attribute__((ext_vector_type(4))) float f32x4;
typedef __attribute__((ext_vector_type(4))) unsigned short u16x4;

__device__ inline unsigned short f2bf(float f) {
    union { float f; unsigned u; } v; v.f = f;
    unsigned r = (v.u + 0x7fff + ((v.u >> 16) & 1)) >> 16;   // RNE
    return (unsigned short)r;
}
__device__ inline float bf2f(unsigned short u) {
    union { unsigned u; float f; } v; v.u = ((unsigned)u) << 16; return v.f;
}

#define GLL16(gp, lp) __builtin_amdgcn_global_load_lds(                      \
    (const __attribute__((address_space(1))) void*)(gp),                     \
    (__attribute__((address_space(3))) void*)(lp), 16, 0, 0)

// ---------------------------------------------------------------------------
// bf16 MFMA GEMM, 2-phase stage-early double-buffered (r11-verified):
// 256x256 tile, BK=32, 8 waves (2x4). STAGE(t+1) issued before compute(t);
// one __syncthreads per tile. 64KB dbuf LDS.
// ---------------------------------------------------------------------------
template<int EPI, int OUT_BF>
__global__ __launch_bounds__(512) void gemm2ph(
    const unsigned short* __restrict__ A,
    const unsigned short* __restrict__ Bt,
    const float* __restrict__ bias,
    void* __restrict__ Cout,
    int M, int Nn, int K, int ldc)
{
    __shared__ unsigned char lds[2][32768];
    const int tid = threadIdx.x;
    const int w = tid >> 6, lane = tid & 63;
    const int lk = lane & 15, lg = lane >> 4;
    const int wr = w >> 2, wc = w & 3;
    const int nbn = Nn >> 8;
    const int nb = gridDim.x;
    int bid = blockIdx.x;
    int swz = (nb & 7) ? bid : (bid & 7) * (nb >> 3) + (bid >> 3);
    const int bm = (swz / nbn) << 8, bn = (swz % nbn) << 8;

    f32x4 acc[8][4] = {};

    auto stage = [&](int buf, int k0) {
        #pragma unroll
        for (int i = 0; i < 4; ++i) {
            int s = tid + i * 512;
            int r = s >> 2, c = s & 3;
            int cs = (c ^ r ^ (r >> 2)) & 3;
            const unsigned short* gp = (r < 256)
                ? A  + (size_t)(bm + r) * K + k0 + cs * 8
                : Bt + (size_t)(bn + (r - 256)) * K + k0 + cs * 8;
            GLL16(gp, &lds[buf][s * 16]);
        }
    };

    const int NT = K >> 5;
    stage(0, 0);
    __syncthreads();
    int cur = 0;
    for (int t = 0; t < NT; ++t) {
        if (t + 1 < NT) stage(cur ^ 1, (t + 1) << 5);
        bf16x8 af[8], bfr[4];
        #pragma unroll
        for (int mi = 0; mi < 8; ++mi) {
            int row = wr * 128 + mi * 16 + lk;
            int sl = (lg ^ row ^ (row >> 2)) & 3;
            af[mi] = *(const bf16x8*)&lds[cur][row * 64 + sl * 16];
        }
        #pragma unroll
        for (int nj = 0; nj < 4; ++nj) {
            int row = wc * 64 + nj * 16 + lk;
            int sl = (lg ^ row ^ (row >> 2)) & 3;
            bfr[nj] = *(const bf16x8*)&lds[cur][16384 + row * 64 + sl * 16];
        }
        #pragma unroll
        for (int mi = 0; mi < 8; ++mi)
            #pragma unroll
            for (int nj = 0; nj < 4; ++nj)
                acc[mi][nj] = __builtin_amdgcn_mfma_f32_16x16x32_bf16(af[mi], bfr[nj], acc[mi][nj], 0, 0, 0);
        __syncthreads();
        cur ^= 1;
    }

    #pragma unroll
    for (int mi = 0; mi < 8; ++mi) {
        int row = bm + wr * 128 + mi * 16 + lg * 4;
        #pragma unroll
        for (int nj = 0; nj < 4; ++nj) {
            int col = bn + wc * 64 + nj * 16 + lk;
            #pragma unroll
            for (int r = 0; r < 4; ++r) {
                float v = acc[mi][nj][r];
                if (EPI >= 1) v += bias[col];
                if (EPI == 2) {
                    float u = v * 0.7978845608f * (1.0f + 0.044715f * v * v);
                    v = v / (1.0f + __expf(-2.0f * u));
                }
                if (OUT_BF)
                    ((unsigned short*)Cout)[(size_t)(row + r) * ldc + col] = f2bf(v);
                else
                    ((float*)Cout)[(size_t)(row + r) * ldc + col] = v;
            }
        }
    }
}

// ---------------------------------------------------------------------------
// bf16 MFMA GEMM, m97 structure, templated BK (r7/r10-verified).
// ---------------------------------------------------------------------------
template<int EPI, int OUT_BF, int BK>
__global__ __launch_bounds__(256) void gemm97(
    const unsigned short* __restrict__ A,
    const unsigned short* __restrict__ Bt,
    const float* __restrict__ bias,
    void* __restrict__ Cout,
    int M, int Nn, int K, int ldc)
{
    constexpr int SPR = BK / 8;
    constexpr int RB  = BK * 2;
    __shared__ unsigned char lds[256 * BK * 2];
    const int tid = threadIdx.x;
    const int w = tid >> 6, lane = tid & 63;
    const int lk = lane & 15, lg = lane >> 4;
    const int wr = w >> 1, wc = w & 1;
    const int nbn = Nn >> 7;
    const int nb = gridDim.x;
    int bid = blockIdx.x;
    int swz = (nb & 7) ? bid : (bid & 7) * (nb >> 3) + (bid >> 3);
    const int bm = (swz / nbn) << 7, bn = (swz % nbn) << 7;

    f32x4 acc[4][4] = {};

    for (int k0 = 0; k0 < K; k0 += BK) {
        #pragma unroll
        for (int i = 0; i < SPR; ++i) {
            int s = tid + i * 256;
            int r = s / SPR, c = s % SPR;
            int cs;
            if constexpr (SPR == 4) cs = (c ^ r ^ (r >> 2)) & 3;
            else                    cs = c ^ (r & 7);
            const unsigned short* gp = (r < 128)
                ? A  + (size_t)(bm + r) * K + k0 + cs * 8
                : Bt + (size_t)(bn + (r - 128)) * K + k0 + cs * 8;
            GLL16(gp, &lds[s * 16]);
        }
        __syncthreads();

        #pragma unroll
        for (int kk = 0; kk < BK / 32; ++kk) {
            bf16x8 af[4], bfr[4];
            #pragma unroll
            for (int m = 0; m < 4; ++m) {
                int row = wr * 64 + m * 16 + lk;
                int sl;
                if constexpr (SPR == 4) sl = ((kk * 4 + lg) ^ row ^ (row >> 2)) & 3;
                else                    sl = (kk * 4 + lg) ^ (row & 7);
                af[m] = *(const bf16x8*)&lds[row * RB + sl * 16];
            }
            #pragma unroll
            for (int n = 0; n < 4; ++n) {
                int row = wc * 64 + n * 16 + lk;
                int sl;
                if constexpr (SPR == 4) sl = ((kk * 4 + lg) ^ row ^ (row >> 2)) & 3;
                else                    sl = (kk * 4 + lg) ^ (row & 7);
                bfr[n] = *(const bf16x8*)&lds[128 * RB + row * RB + sl * 16];
            }
            #pragma unroll
            for (int m = 0; m < 4; ++m)
                #pragma unroll
                for (int n = 0; n < 4; ++n)
                    acc[m][n] = __builtin_amdgcn_mfma_f32_16x16x32_bf16(af[m], bfr[n], acc[m][n], 0, 0, 0);
        }
        __syncthreads();
    }

    #pragma unroll
    for (int m = 0; m < 4; ++m) {
        int row = bm + wr * 64 + m * 16 + lg * 4;
        #pragma unroll
        for (int n = 0; n < 4; ++n) {
            int col = bn + wc * 64 + n * 16 + lk;
            #pragma unroll
            for (int r = 0; r < 4; ++r) {
                float v = acc[m][n][r];
                if (EPI >= 1) v += bias[col];
                if (EPI == 2) {
                    float u = v * 0.7978845608f * (1.0f + 0.044715f * v * v);
                    v = v / (1.0f + __expf(-2.0f * u));
                }
                if (OUT_BF)
                    ((unsigned short*)Cout)[(size_t)(row + r) * ldc + col] = f2bf(v);
                else
                    ((float*)Cout)[(size_t)(row + r) * ldc + col] = v;
            }
        }
    }
}

// ---------------------------------------------------------------------------
__global__ __launch_bounds__(256) void cvt_bf16(
    const float* __restrict__ src, unsigned short* __restrict__ dst, int n)
{
    int i = (blockIdx.x * 256 + threadIdx.x) * 4;
    if (i < n) {
        float4 v = *(const float4*)(src + i);
        u16x4 o = { f2bf(v.x), f2bf(v.y), f2bf(v.z), f2bf(v.w) };
        *(u16x4*)(dst + i) = o;
    }
}

// ---------------------------------------------------------------------------
__global__ __launch_bounds__(256) void transpose_cvt(
    const float* __restrict__ src, unsigned short* __restrict__ dst, int R, int Cc)
{
    __shared__ float t[32][33];
    const int bc = blockIdx.x * 32, br = blockIdx.y * 32;
    const int tx = threadIdx.x & 31, ty = threadIdx.x >> 5;
    #pragma unroll
    for (int i = 0; i < 4; ++i)
        t[ty + i * 8][tx] = src[(size_t)(br + ty + i * 8) * Cc + bc + tx];
    __syncthreads();
    #pragma unroll
    for (int i = 0; i < 4; ++i)
        dst[(size_t)(bc + ty + i * 8) * R + br + tx] = f2bf(t[tx][ty + i * 8]);
}

// ---------------------------------------------------------------------------
__global__ __launch_bounds__(256) void drofe_bf(
    const unsigned short* __restrict__ QK, unsigned short* __restrict__ Qo,
    unsigned short* __restrict__ Ko,
    const float* __restrict__ freqband, const float* __restrict__ demo, int N)
{
    const float PI_F = 3.14159265358979323846f;
    int idx = blockIdx.x * 256 + threadIdx.x;
    int col2 = idx & 511;
    int row  = idx >> 9;
    int n = row & (N - 1), b = row >> 10;
    int i  = col2 & 31;
    int ii = (i < 16) ? i : i - 16;
    float fb = (i < 16) ? freqband[n * 2 + 0] : freqband[n * 2 + 1];
    float freq = (1.0f + (float)ii * (4.0f / 15.0f)) * PI_F;
    float ang = fb * freq;
    float cv = cosf(ang), sv = sinf(ang);
    float ca = cv * demo[b * 2 + 0];
    float sg = sv * demo[b * 2 + 1];
    const unsigned* qk = (const unsigned*)(QK + (size_t)row * 2048);
    unsigned qu = qk[col2], ku = qk[512 + col2];
    float qe = bf2f((unsigned short)qu), qo_ = bf2f((unsigned short)(qu >> 16));
    float ke = bf2f((unsigned short)ku), ko_ = bf2f((unsigned short)(ku >> 16));
    const float s8 = 0.125f;
    unsigned qres = (unsigned)f2bf((qe * ca - qo_ * sg) * s8)
                  | ((unsigned)f2bf((qo_ * ca + qe * sg) * s8) << 16);
    unsigned kres = (unsigned)f2bf(ke * ca - ko_ * sg)
                  | ((unsigned)f2bf(ko_ * ca + ke * sg) << 16);
    ((unsigned*)Qo)[(size_t)row * 512 + col2] = qres;
    ((unsigned*)Ko)[(size_t)row * 512 + col2] = kres;
}

// ---------------------------------------------------------------------------
// Flash attention, bf16 in/out, MFMA 16x16x32, fp32 accum.
// r14: SWAPPED operands — S^T = mfma(kf, qf), O^T = mfma(vf, pf).
// kf/qf/vf fragment READS identical to the verified kernel; outputs land as
// C[col = q = lk][row = (lg*4+r)]. Each lane owns ONE q-row: row-reduce is
// 15 in-lane fmax + 2 shuffles (was 32 shuffles); corr/m/l are lane scalars.
// P^T kept per-q in Ps[16][72]; pf read = contiguous b128 (B-frag direct).
// ---------------------------------------------------------------------------
__global__ __launch_bounds__(256) void attn_mfma(
    const unsigned short* __restrict__ Q, const unsigned short* __restrict__ K,
    const unsigned short* __restrict__ V, unsigned short* __restrict__ O,
    int B, int H, int N)
{
    __shared__ unsigned short Ks[64 * 64];
    __shared__ unsigned short Vt[64 * 72];
    __shared__ unsigned short Ps[4][16 * 72];

    const int bi = blockIdx.x;
    const int bh = (bi & 7) + 8 * ((bi >> 3) & 15);
    const int q0 = (bi >> 7) * 64;
    const int b = bh >> 4, h = bh & 15;
    const int tid = threadIdx.x;
    const int w = tid >> 6, lane = tid & 63;
    const int lg = lane >> 4, lk = lane & 15;

    bf16x8 qf[2];                               // Q[q=w*16+lk][kh*32+lg*8+j]
    {
        const unsigned short* qrow = Q + (size_t)(b * N + q0 + w * 16 + lk) * 1024 + h * 64;
        qf[0] = *(const bf16x8*)(qrow + lg * 8);
        qf[1] = *(const bf16x8*)(qrow + 32 + lg * 8);
    }

    f32x4 o[4] = {};                            // o[ds][r] = O[q=lk][ds*16+lg*4+r]
    float m_run = -INFINITY, l_run = 0.f;

    for (int t0 = 0; t0 < N; t0 += 64) {
        const size_t kvbase = (size_t)(b * N + t0) * 1024 + h * 64;
        #pragma unroll
        for (int it = 0; it < 2; ++it) {        // K: swizzled-source GLL (r4-verified)
            int s = it * 256 + tid;
            int row = s >> 3, cb = (s & 7) << 4;
            int dby = cb ^ ((row & 7) << 4);
            GLL16(K + kvbase + (size_t)row * 1024 + (dby >> 1), &Ks[s * 8]);
        }
        {                                       // V: reg-staged transpose (r11 form)
            int c = tid >> 5, k0 = (tid & 31) * 2;
            const unsigned short* vp = V + kvbase + (size_t)k0 * 1024 + c * 8;
            u16x8 va = *(const u16x8*)vp;
            u16x8 vb = *(const u16x8*)(vp + 1024);
            #pragma unroll
            for (int j = 0; j < 8; ++j) {
                unsigned val = (unsigned)va[j] | ((unsigned)vb[j] << 16);
                *(unsigned*)&Vt[(c * 8 + j) * 72 + k0] = val;
            }
        }
        __syncthreads();

        // S^T = mfma(kf, qf): s4[sub][r] = S[q=lk][key=sub*16+lg*4+r]
        f32x4 s4[4];
        #pragma unroll
        for (int sub = 0; sub < 4; ++sub) {
            f32x4 acc = {0.f, 0.f, 0.f, 0.f};
            #pragma unroll
            for (int kh = 0; kh < 2; ++kh) {
                int cc = (kh * 64 + lg * 16) ^ ((lk & 7) << 4);
                bf16x8 kf = *(const bf16x8*)&Ks[(sub * 16 + lk) * 64 + (cc >> 1)];
                acc = __builtin_amdgcn_mfma_f32_16x16x32_bf16(kf, qf[kh], acc, 0, 0, 0);
            }
            s4[sub] = acc;
        }

        // in-register softmax for q = lk (lane-local row)
        float tm = -INFINITY;
        #pragma unroll
        for (int sub = 0; sub < 4; ++sub)
            #pragma unroll
            for (int r = 0; r < 4; ++r) tm = fmaxf(tm, s4[sub][r]);
        tm = fmaxf(tm, __shfl_xor(tm, 16));
        tm = fmaxf(tm, __shfl_xor(tm, 32));
        float mn = fmaxf(m_run, tm);
        float corr = __expf(m_run - mn);
        m_run = mn;
        float psum = 0.f;
        unsigned pw[4][2];
        #pragma unroll
        for (int sub = 0; sub < 4; ++sub) {
            float p0 = __expf(s4[sub][0] - mn);
            float p1 = __expf(s4[sub][1] - mn);
            float p2 = __expf(s4[sub][2] - mn);
            float p3 = __expf(s4[sub][3] - mn);
            psum += (p0 + p1) + (p2 + p3);
            pw[sub][0] = (__float_as_uint(p0) >> 16) | (__float_as_uint(p1) & 0xffff0000u);
            pw[sub][1] = (__float_as_uint(p2) >> 16) | (__float_as_uint(p3) & 0xffff0000u);
        }
        psum += __shfl_xor(psum, 16);
        psum += __shfl_xor(psum, 32);
        l_run = l_run * corr + psum;
        #pragma unroll
        for (int ds = 0; ds < 4; ++ds)
            #pragma unroll
            for (int r = 0; r < 4; ++r) o[ds][r] *= corr;
        // Ps[q=lk][key]: keys sub*16+lg*4+{0..3} as 2 u32 per sub
        #pragma unroll
        for (int sub = 0; sub < 4; ++sub) {
            *(unsigned*)&Ps[w][lk * 72 + sub * 16 + lg * 4]     = pw[sub][0];
            *(unsigned*)&Ps[w][lk * 72 + sub * 16 + lg * 4 + 2] = pw[sub][1];
        }
        asm volatile("s_waitcnt lgkmcnt(0)" ::: "memory");   // per-wave P RAW

        // O^T += mfma(vf, pf): pf = P[q=lk][kh*32+lg*8+j] contiguous b128
        #pragma unroll
        for (int kh = 0; kh < 2; ++kh) {
            bf16x8 pf = *(const bf16x8*)&Ps[w][lk * 72 + kh * 32 + lg * 8];
            #pragma unroll
            for (int ds = 0; ds < 4; ++ds) {
                bf16x8 vf = *(const bf16x8*)&Vt[(ds * 16 + lk) * 72 + kh * 32 + lg * 8];
                o[ds] = __builtin_amdgcn_mfma_f32_16x16x32_bf16(vf, pf, o[ds], 0, 0, 0);
            }
        }
        __syncthreads();
    }

    // write O[q=w*16+lk][d=ds*16+lg*4+{0..3}] as 8B stores
    {
        unsigned short* orow = O + (size_t)(b * N + q0 + w * 16 + lk) * 1024 + h * 64;
        float rinv = 1.0f / l_run;
        #pragma unroll
        for (int ds = 0; ds < 4; ++ds) {
            u16x4 pk = { f2bf(o[ds][0] * rinv), f2bf(o[ds][1] * rinv),
                         f2bf(o[ds][2] * rinv), f2bf(o[ds][3] * rinv) };
            *(u16x4*)(orow + ds * 16 + lg * 4) = pk;
        }
    }
}

// ---------------------------------------------------------------------------
__global__ __launch_bounds__(256) void ln_res_kernel(
    const float* __restrict__ x, const float* __restrict__ y,
    const float* __restrict__ gamma, const float* __restrict__ w,
    const float* __restrict__ bia, float* __restrict__ out,
    unsigned short* __restrict__ out_bf, int C)
{
    const int row = blockIdx.x;
    __shared__ float buf[1024];
    __shared__ float red[8];
    const size_t base = (size_t)row * C;
    float s = 0.f, ss = 0.f;
    for (int c = threadIdx.x; c < C; c += 256) {
        float v = x[base + c] + gamma[c] * y[base + c];
        buf[c] = v; s += v; ss += v * v;
    }
    #pragma unroll
    for (int msk = 1; msk < 64; msk <<= 1) { s += __shfl_xor(s, msk); ss += __shfl_xor(ss, msk); }
    int wv = threadIdx.x >> 6, lane = threadIdx.x & 63;
    if (lane == 0) { red[wv * 2] = s; red[wv * 2 + 1] = ss; }
    __syncthreads();
    if (threadIdx.x == 0) {
        float S = 0.f, SS = 0.f;
        #pragma unroll
        for (int i = 0; i < 4; ++i) { S += red[2 * i]; SS += red[2 * i + 1]; }
        red[0] = S; red[1] = SS;
    }
    __syncthreads();
    float mu = red[0] / C;
    float var = red[1] / C - mu * mu;
    float rstd = rsqrtf(var + 1e-5f);
    for (int c = threadIdx.x; c < C; c += 256) {
        float v = (buf[c] - mu) * rstd * w[c] + bia[c];
        out[base + c] = v;
        if (out_bf) out_bf[base + c] = f2bf(v);
    }
}

// ---------------------------------------------------------------------------
extern "C" void kernel_launch(void* const* d_in, const int* in_sizes, int n_in,
                              void* d_out, int out_size, void* d_ws, size_t ws_size,
                              hipStream_t stream)
{
    const float* x      = (const float*)d_in[0];
    const float* demo   = (const float*)d_in[1];
    const float* expl   = (const float*)d_in[2];
    const float* fb     = (const float*)d_in[3];
    const float* w_qkv  = (const float*)d_in[4];
    const float* w_proj = (const float*)d_in[5];
    const float* b_proj = (const float*)d_in[6];
    const float* gamma1 = (const float*)d_in[7];
    const float* gamma2 = (const float*)d_in[8];
    const float* ln1_w  = (const float*)d_in[9];
    const float* ln1_b  = (const float*)d_in[10];
    const float* ln2_w  = (const float*)d_in[11];
    const float* ln2_b  = (const float*)d_in[12];
    const float* w1     = (const float*)d_in[13];
    const float* b1     = (const float*)d_in[14];
    const float* w2     = (const float*)d_in[15];
    const float* b2     = (const float*)d_in[16];
    float* out = (float*)d_out;

    const int B = 8, N = 1024, C = 1024, F = 4096, H = 16;
    const int M = B * N;                        // 8192
    const size_t Mi = 1048576;

    float* ws = (float*)d_ws;
    unsigned short* QKbf = (unsigned short*)ws;              // M x 2048 bf16
    unsigned short* Obf  = (unsigned short*)ws;              // M x 1024 bf16
    float*          H2   = ws;                               // M x 1024 f32
    unsigned short* Qbf  = (unsigned short*)(ws + 8 * Mi);   // M x 1024 bf16
    unsigned short* Kbf  = (unsigned short*)(ws + 12 * Mi);
    unsigned short* Vbf  = (unsigned short*)(ws + 16 * Mi);
    unsigned short* Hid  = (unsigned short*)(ws + 8 * Mi);   // M x 4096 bf16
    unsigned short* Ebf  = (unsigned short*)(ws + 24 * Mi);
    unsigned short* Xbf  = (unsigned short*)(ws + 28 * Mi);
    float*          Pb   = ws + 24 * Mi;                     // M x 1024 f32
    float*          X1   = ws + 32 * Mi;                     // M x 1024 f32
    unsigned short* X1bf = (unsigned short*)(ws + 40 * Mi);
    unsigned short* Wt   = (unsigned short*)(ws + 44 * Mi);
    unsigned short* wqkvT  = Wt;                             // [3072][1024]
    unsigned short* wprojT = Wt + (size_t)3145728;           // [1024][1024]
    unsigned short* w1T    = wprojT + (size_t)1048576;       // [4096][1024]
    unsigned short* w2T    = w1T + (size_t)4194304;          // [1024][4096]

    dim3 blk(256);
    dim3 blk5(512);
    const int MC = M * C;

    hipLaunchKernelGGL(cvt_bf16, dim3(MC / 1024), blk, 0, stream, expl, Ebf, MC);
    hipLaunchKernelGGL(cvt_bf16, dim3(MC / 1024), blk, 0, stream, x, Xbf, MC);
    hipLaunchKernelGGL(transpose_cvt, dim3(96, 32), blk, 0, stream, w_qkv, wqkvT, C, 3 * C);
    hipLaunchKernelGGL(transpose_cvt, dim3(32, 32), blk, 0, stream, w_proj, wprojT, C, C);
    hipLaunchKernelGGL(transpose_cvt, dim3(128, 32), blk, 0, stream, w1, w1T, C, F);
    hipLaunchKernelGGL(transpose_cvt, dim3(32, 128), blk, 0, stream, w2, w2T, F, C);

    // QK projection [2ph 256^2]; V projection [gemm97 BK=32]
    hipLaunchKernelGGL((gemm2ph<0,1>), dim3(32 * 8), blk5, 0, stream, Ebf, wqkvT, (const float*)nullptr, (void*)QKbf, M, 2048, C, 2048);
    hipLaunchKernelGGL((gemm97<0,1,32>), dim3(64 * 8), blk, 0, stream, Xbf, wqkvT + (size_t)2048 * 1024, (const float*)nullptr, (void*)Vbf, M, 1024, C, 1024);

    // drofe: bf16 QK -> rotated bf16 Q (scaled), K
    hipLaunchKernelGGL(drofe_bf, dim3(M * 512 / 256), blk, 0, stream, QKbf, Qbf, Kbf, fb, demo, N);

    // attention -> bf16 O
    hipLaunchKernelGGL(attn_mfma, dim3(B * H * (N / 64)), blk, 0, stream, Qbf, Kbf, Vbf, Obf, B, H, N);

    // output projection [gemm97 BK=32]
    hipLaunchKernelGGL((gemm97<1,0,32>), dim3(64 * 8), blk, 0, stream, Obf, wprojT, b_proj, (void*)Pb, M, 1024, C, 1024);

    // residual + LN1 (f32 + bf16)
    hipLaunchKernelGGL(ln_res_kernel, dim3(M), blk, 0, stream, x, Pb, gamma1, ln1_w, ln1_b, X1, X1bf, C);

    // MLP: MLP1 [2ph 256^2, fast gelu], MLP2 [gemm97 BK=64]
    hipLaunchKernelGGL((gemm2ph<2,1>), dim3(32 * 16), blk5, 0, stream, X1bf, w1T, b1, (void*)Hid, M, F, C, F);
    hipLaunchKernelGGL((gemm97<1,0,64>), dim3(64 * 8), blk, 0, stream, Hid, w2T, b2, (void*)H2, M, 1024, F, 1024);

    // residual + LN2 -> out
    hipLaunchKernelGGL(ln_res_kernel, dim3(M), blk, 0, stream, X1, H2, gamma2, ln2_w, ln2_b, out, (unsigned short*)nullptr, C);
}

// Round 15
// 426.356 us; speedup vs baseline: 1.1152x; 1.0074x over previous
//
#include <hip/hip_runtime.h>
#include <hip/hip_bf16.h>
#include <math.h>

typedef __attribute__((ext_vector_type(8))) short bf16x8;
typedef __attribute__((ext_vector_type(8))) unsigned short u16x8;
typedef __attribute__((ext_vector_type(4))) float f32x4;
typedef __attribute__((ext_vector_type(4))) unsigned short u16x4;

__device__ inline unsigned short f2bf(float f) {
    union { float f; unsigned u; } v; v.f = f;
    unsigned r = (v.u + 0x7fff + ((v.u >> 16) & 1)) >> 16;   // RNE
    return (unsigned short)r;
}
__device__ inline float bf2f(unsigned short u) {
    union { unsigned u; float f; } v; v.u = ((unsigned)u) << 16; return v.f;
}

#define GLL16(gp, lp) __builtin_amdgcn_global_load_lds(                      \
    (const __attribute__((address_space(1))) void*)(gp),                     \
    (__attribute__((address_space(3))) void*)(lp), 16, 0, 0)

// ---------------------------------------------------------------------------
// bf16 MFMA GEMM, m97 structure + FORCED 4 waves/EU occupancy:
// 128x128 tile, 4 waves (2x2), per-wave 64x64 = 4x4 frags (64 acc regs).
// __launch_bounds__(256, 4) caps VGPR+AGPR at 128/wave -> 16 waves/CU
// (~4 blocks resident), doubling the 8-10 waves/CU all prior structures
// parked at (216 regs for 2ph's 128-acc tile = 2 waves/SIMD; the measured
// 21.8% occupancy). Plateau mechanism = register-occupancy, not schedule.
// BK templated; swizzle involutions as r10 (residual 2-way = free, m136).
// EPI: 0=none 1=+bias 2=+bias+gelu(tanh-approx). OUT_BF: bf16 output.
// ---------------------------------------------------------------------------
template<int EPI, int OUT_BF, int BK>
__global__ __launch_bounds__(256, 4) void gemm97o(
    const unsigned short* __restrict__ A,
    const unsigned short* __restrict__ Bt,
    const float* __restrict__ bias,
    void* __restrict__ Cout,
    int M, int Nn, int K, int ldc)
{
    constexpr int SPR = BK / 8;
    constexpr int RB  = BK * 2;
    __shared__ unsigned char lds[256 * BK * 2];
    const int tid = threadIdx.x;
    const int w = tid >> 6, lane = tid & 63;
    const int lk = lane & 15, lg = lane >> 4;
    const int wr = w >> 1, wc = w & 1;
    const int nbn = Nn >> 7;
    const int nb = gridDim.x;
    int bid = blockIdx.x;
    int swz = (nb & 7) ? bid : (bid & 7) * (nb >> 3) + (bid >> 3);
    const int bm = (swz / nbn) << 7, bn = (swz % nbn) << 7;

    f32x4 acc[4][4] = {};

    for (int k0 = 0; k0 < K; k0 += BK) {
        #pragma unroll
        for (int i = 0; i < SPR; ++i) {
            int s = tid + i * 256;
            int r = s / SPR, c = s % SPR;
            int cs;
            if constexpr (SPR == 4) cs = (c ^ r ^ (r >> 2)) & 3;
            else                    cs = c ^ (r & 7);
            const unsigned short* gp = (r < 128)
                ? A  + (size_t)(bm + r) * K + k0 + cs * 8
                : Bt + (size_t)(bn + (r - 128)) * K + k0 + cs * 8;
            GLL16(gp, &lds[s * 16]);
        }
        __syncthreads();

        #pragma unroll
        for (int kk = 0; kk < BK / 32; ++kk) {
            bf16x8 af[4], bfr[4];
            #pragma unroll
            for (int m = 0; m < 4; ++m) {
                int row = wr * 64 + m * 16 + lk;
                int sl;
                if constexpr (SPR == 4) sl = ((kk * 4 + lg) ^ row ^ (row >> 2)) & 3;
                else                    sl = (kk * 4 + lg) ^ (row & 7);
                af[m] = *(const bf16x8*)&lds[row * RB + sl * 16];
            }
            #pragma unroll
            for (int n = 0; n < 4; ++n) {
                int row = wc * 64 + n * 16 + lk;
                int sl;
                if constexpr (SPR == 4) sl = ((kk * 4 + lg) ^ row ^ (row >> 2)) & 3;
                else                    sl = (kk * 4 + lg) ^ (row & 7);
                bfr[n] = *(const bf16x8*)&lds[128 * RB + row * RB + sl * 16];
            }
            #pragma unroll
            for (int m = 0; m < 4; ++m)
                #pragma unroll
                for (int n = 0; n < 4; ++n)
                    acc[m][n] = __builtin_amdgcn_mfma_f32_16x16x32_bf16(af[m], bfr[n], acc[m][n], 0, 0, 0);
        }
        __syncthreads();
    }

    #pragma unroll
    for (int m = 0; m < 4; ++m) {
        int row = bm + wr * 64 + m * 16 + lg * 4;
        #pragma unroll
        for (int n = 0; n < 4; ++n) {
            int col = bn + wc * 64 + n * 16 + lk;
            #pragma unroll
            for (int r = 0; r < 4; ++r) {
                float v = acc[m][n][r];
                if (EPI >= 1) v += bias[col];
                if (EPI == 2) {
                    float u = v * 0.7978845608f * (1.0f + 0.044715f * v * v);
                    v = v / (1.0f + __expf(-2.0f * u));
                }
                if (OUT_BF)
                    ((unsigned short*)Cout)[(size_t)(row + r) * ldc + col] = f2bf(v);
                else
                    ((float*)Cout)[(size_t)(row + r) * ldc + col] = v;
            }
        }
    }
}

// ---------------------------------------------------------------------------
__global__ __launch_bounds__(256) void cvt_bf16(
    const float* __restrict__ src, unsigned short* __restrict__ dst, int n)
{
    int i = (blockIdx.x * 256 + threadIdx.x) * 4;
    if (i < n) {
        float4 v = *(const float4*)(src + i);
        u16x4 o = { f2bf(v.x), f2bf(v.y), f2bf(v.z), f2bf(v.w) };
        *(u16x4*)(dst + i) = o;
    }
}

// ---------------------------------------------------------------------------
__global__ __launch_bounds__(256) void transpose_cvt(
    const float* __restrict__ src, unsigned short* __restrict__ dst, int R, int Cc)
{
    __shared__ float t[32][33];
    const int bc = blockIdx.x * 32, br = blockIdx.y * 32;
    const int tx = threadIdx.x & 31, ty = threadIdx.x >> 5;
    #pragma unroll
    for (int i = 0; i < 4; ++i)
        t[ty + i * 8][tx] = src[(size_t)(br + ty + i * 8) * Cc + bc + tx];
    __syncthreads();
    #pragma unroll
    for (int i = 0; i < 4; ++i)
        dst[(size_t)(bc + ty + i * 8) * R + br + tx] = f2bf(t[tx][ty + i * 8]);
}

// ---------------------------------------------------------------------------
__global__ __launch_bounds__(256) void drofe_bf(
    const unsigned short* __restrict__ QK, unsigned short* __restrict__ Qo,
    unsigned short* __restrict__ Ko,
    const float* __restrict__ freqband, const float* __restrict__ demo, int N)
{
    const float PI_F = 3.14159265358979323846f;
    int idx = blockIdx.x * 256 + threadIdx.x;
    int col2 = idx & 511;
    int row  = idx >> 9;
    int n = row & (N - 1), b = row >> 10;
    int i  = col2 & 31;
    int ii = (i < 16) ? i : i - 16;
    float fb = (i < 16) ? freqband[n * 2 + 0] : freqband[n * 2 + 1];
    float freq = (1.0f + (float)ii * (4.0f / 15.0f)) * PI_F;
    float ang = fb * freq;
    float cv = cosf(ang), sv = sinf(ang);
    float ca = cv * demo[b * 2 + 0];
    float sg = sv * demo[b * 2 + 1];
    const unsigned* qk = (const unsigned*)(QK + (size_t)row * 2048);
    unsigned qu = qk[col2], ku = qk[512 + col2];
    float qe = bf2f((unsigned short)qu), qo_ = bf2f((unsigned short)(qu >> 16));
    float ke = bf2f((unsigned short)ku), ko_ = bf2f((unsigned short)(ku >> 16));
    const float s8 = 0.125f;
    unsigned qres = (unsigned)f2bf((qe * ca - qo_ * sg) * s8)
                  | ((unsigned)f2bf((qo_ * ca + qe * sg) * s8) << 16);
    unsigned kres = (unsigned)f2bf(ke * ca - ko_ * sg)
                  | ((unsigned)f2bf(ko_ * ca + ke * sg) << 16);
    ((unsigned*)Qo)[(size_t)row * 512 + col2] = qres;
    ((unsigned*)Ko)[(size_t)row * 512 + col2] = kres;
}

// ---------------------------------------------------------------------------
// Flash attention, swapped-operand (r14-verified): S^T = mfma(kf,qf),
// O^T = mfma(vf,pf); lane-local softmax (2 shuffles per tile).
// ---------------------------------------------------------------------------
__global__ __launch_bounds__(256) void attn_mfma(
    const unsigned short* __restrict__ Q, const unsigned short* __restrict__ K,
    const unsigned short* __restrict__ V, unsigned short* __restrict__ O,
    int B, int H, int N)
{
    __shared__ unsigned short Ks[64 * 64];
    __shared__ unsigned short Vt[64 * 72];
    __shared__ unsigned short Ps[4][16 * 72];

    const int bi = blockIdx.x;
    const int bh = (bi & 7) + 8 * ((bi >> 3) & 15);
    const int q0 = (bi >> 7) * 64;
    const int b = bh >> 4, h = bh & 15;
    const int tid = threadIdx.x;
    const int w = tid >> 6, lane = tid & 63;
    const int lg = lane >> 4, lk = lane & 15;

    bf16x8 qf[2];
    {
        const unsigned short* qrow = Q + (size_t)(b * N + q0 + w * 16 + lk) * 1024 + h * 64;
        qf[0] = *(const bf16x8*)(qrow + lg * 8);
        qf[1] = *(const bf16x8*)(qrow + 32 + lg * 8);
    }

    f32x4 o[4] = {};
    float m_run = -INFINITY, l_run = 0.f;

    for (int t0 = 0; t0 < N; t0 += 64) {
        const size_t kvbase = (size_t)(b * N + t0) * 1024 + h * 64;
        #pragma unroll
        for (int it = 0; it < 2; ++it) {
            int s = it * 256 + tid;
            int row = s >> 3, cb = (s & 7) << 4;
            int dby = cb ^ ((row & 7) << 4);
            GLL16(K + kvbase + (size_t)row * 1024 + (dby >> 1), &Ks[s * 8]);
        }
        {
            int c = tid >> 5, k0 = (tid & 31) * 2;
            const unsigned short* vp = V + kvbase + (size_t)k0 * 1024 + c * 8;
            u16x8 va = *(const u16x8*)vp;
            u16x8 vb = *(const u16x8*)(vp + 1024);
            #pragma unroll
            for (int j = 0; j < 8; ++j) {
                unsigned val = (unsigned)va[j] | ((unsigned)vb[j] << 16);
                *(unsigned*)&Vt[(c * 8 + j) * 72 + k0] = val;
            }
        }
        __syncthreads();

        f32x4 s4[4];
        #pragma unroll
        for (int sub = 0; sub < 4; ++sub) {
            f32x4 acc = {0.f, 0.f, 0.f, 0.f};
            #pragma unroll
            for (int kh = 0; kh < 2; ++kh) {
                int cc = (kh * 64 + lg * 16) ^ ((lk & 7) << 4);
                bf16x8 kf = *(const bf16x8*)&Ks[(sub * 16 + lk) * 64 + (cc >> 1)];
                acc = __builtin_amdgcn_mfma_f32_16x16x32_bf16(kf, qf[kh], acc, 0, 0, 0);
            }
            s4[sub] = acc;
        }

        float tm = -INFINITY;
        #pragma unroll
        for (int sub = 0; sub < 4; ++sub)
            #pragma unroll
            for (int r = 0; r < 4; ++r) tm = fmaxf(tm, s4[sub][r]);
        tm = fmaxf(tm, __shfl_xor(tm, 16));
        tm = fmaxf(tm, __shfl_xor(tm, 32));
        float mn = fmaxf(m_run, tm);
        float corr = __expf(m_run - mn);
        m_run = mn;
        float psum = 0.f;
        unsigned pw[4][2];
        #pragma unroll
        for (int sub = 0; sub < 4; ++sub) {
            float p0 = __expf(s4[sub][0] - mn);
            float p1 = __expf(s4[sub][1] - mn);
            float p2 = __expf(s4[sub][2] - mn);
            float p3 = __expf(s4[sub][3] - mn);
            psum += (p0 + p1) + (p2 + p3);
            pw[sub][0] = (__float_as_uint(p0) >> 16) | (__float_as_uint(p1) & 0xffff0000u);
            pw[sub][1] = (__float_as_uint(p2) >> 16) | (__float_as_uint(p3) & 0xffff0000u);
        }
        psum += __shfl_xor(psum, 16);
        psum += __shfl_xor(psum, 32);
        l_run = l_run * corr + psum;
        #pragma unroll
        for (int ds = 0; ds < 4; ++ds)
            #pragma unroll
            for (int r = 0; r < 4; ++r) o[ds][r] *= corr;
        #pragma unroll
        for (int sub = 0; sub < 4; ++sub) {
            *(unsigned*)&Ps[w][lk * 72 + sub * 16 + lg * 4]     = pw[sub][0];
            *(unsigned*)&Ps[w][lk * 72 + sub * 16 + lg * 4 + 2] = pw[sub][1];
        }
        asm volatile("s_waitcnt lgkmcnt(0)" ::: "memory");

        #pragma unroll
        for (int kh = 0; kh < 2; ++kh) {
            bf16x8 pf = *(const bf16x8*)&Ps[w][lk * 72 + kh * 32 + lg * 8];
            #pragma unroll
            for (int ds = 0; ds < 4; ++ds) {
                bf16x8 vf = *(const bf16x8*)&Vt[(ds * 16 + lk) * 72 + kh * 32 + lg * 8];
                o[ds] = __builtin_amdgcn_mfma_f32_16x16x32_bf16(vf, pf, o[ds], 0, 0, 0);
            }
        }
        __syncthreads();
    }

    {
        unsigned short* orow = O + (size_t)(b * N + q0 + w * 16 + lk) * 1024 + h * 64;
        float rinv = 1.0f / l_run;
        #pragma unroll
        for (int ds = 0; ds < 4; ++ds) {
            u16x4 pk = { f2bf(o[ds][0] * rinv), f2bf(o[ds][1] * rinv),
                         f2bf(o[ds][2] * rinv), f2bf(o[ds][3] * rinv) };
            *(u16x4*)(orow + ds * 16 + lg * 4) = pk;
        }
    }
}

// ---------------------------------------------------------------------------
// Fused residual + LayerNorm: out = LN(x + gamma*bf2f(y)) * w + b
// (y is bf16 now — halves the GEMM-output round-trip traffic)
// ---------------------------------------------------------------------------
__global__ __launch_bounds__(256) void ln_res_kernel(
    const float* __restrict__ x, const unsigned short* __restrict__ y,
    const float* __restrict__ gamma, const float* __restrict__ w,
    const float* __restrict__ bia, float* __restrict__ out,
    unsigned short* __restrict__ out_bf, int C)
{
    const int row = blockIdx.x;
    __shared__ float buf[1024];
    __shared__ float red[8];
    const size_t base = (size_t)row * C;
    float s = 0.f, ss = 0.f;
    for (int c = threadIdx.x; c < C; c += 256) {
        float v = x[base + c] + gamma[c] * bf2f(y[base + c]);
        buf[c] = v; s += v; ss += v * v;
    }
    #pragma unroll
    for (int msk = 1; msk < 64; msk <<= 1) { s += __shfl_xor(s, msk); ss += __shfl_xor(ss, msk); }
    int wv = threadIdx.x >> 6, lane = threadIdx.x & 63;
    if (lane == 0) { red[wv * 2] = s; red[wv * 2 + 1] = ss; }
    __syncthreads();
    if (threadIdx.x == 0) {
        float S = 0.f, SS = 0.f;
        #pragma unroll
        for (int i = 0; i < 4; ++i) { S += red[2 * i]; SS += red[2 * i + 1]; }
        red[0] = S; red[1] = SS;
    }
    __syncthreads();
    float mu = red[0] / C;
    float var = red[1] / C - mu * mu;
    float rstd = rsqrtf(var + 1e-5f);
    for (int c = threadIdx.x; c < C; c += 256) {
        float v = (buf[c] - mu) * rstd * w[c] + bia[c];
        out[base + c] = v;
        if (out_bf) out_bf[base + c] = f2bf(v);
    }
}

// ---------------------------------------------------------------------------
extern "C" void kernel_launch(void* const* d_in, const int* in_sizes, int n_in,
                              void* d_out, int out_size, void* d_ws, size_t ws_size,
                              hipStream_t stream)
{
    const float* x      = (const float*)d_in[0];
    const float* demo   = (const float*)d_in[1];
    const float* expl   = (const float*)d_in[2];
    const float* fb     = (const float*)d_in[3];
    const float* w_qkv  = (const float*)d_in[4];
    const float* w_proj = (const float*)d_in[5];
    const float* b_proj = (const float*)d_in[6];
    const float* gamma1 = (const float*)d_in[7];
    const float* gamma2 = (const float*)d_in[8];
    const float* ln1_w  = (const float*)d_in[9];
    const float* ln1_b  = (const float*)d_in[10];
    const float* ln2_w  = (const float*)d_in[11];
    const float* ln2_b  = (const float*)d_in[12];
    const float* w1     = (const float*)d_in[13];
    const float* b1     = (const float*)d_in[14];
    const float* w2     = (const float*)d_in[15];
    const float* b2     = (const float*)d_in[16];
    float* out = (float*)d_out;

    const int B = 8, N = 1024, C = 1024, F = 4096, H = 16;
    const int M = B * N;                        // 8192
    const size_t Mi = 1048576;

    float* ws = (float*)d_ws;
    unsigned short* QKbf = (unsigned short*)ws;              // M x 2048 bf16
    unsigned short* Obf  = (unsigned short*)ws;              // M x 1024 bf16
    unsigned short* H2   = (unsigned short*)ws;              // M x 1024 bf16
    unsigned short* Qbf  = (unsigned short*)(ws + 8 * Mi);   // M x 1024 bf16
    unsigned short* Kbf  = (unsigned short*)(ws + 12 * Mi);
    unsigned short* Vbf  = (unsigned short*)(ws + 16 * Mi);
    unsigned short* Hid  = (unsigned short*)(ws + 8 * Mi);   // M x 4096 bf16
    unsigned short* Ebf  = (unsigned short*)(ws + 24 * Mi);
    unsigned short* Xbf  = (unsigned short*)(ws + 28 * Mi);
    unsigned short* Pb   = (unsigned short*)(ws + 24 * Mi);  // M x 1024 bf16
    float*          X1   = ws + 32 * Mi;                     // M x 1024 f32
    unsigned short* X1bf = (unsigned short*)(ws + 40 * Mi);
    unsigned short* Wt   = (unsigned short*)(ws + 44 * Mi);
    unsigned short* wqkvT  = Wt;                             // [3072][1024]
    unsigned short* wprojT = Wt + (size_t)3145728;           // [1024][1024]
    unsigned short* w1T    = wprojT + (size_t)1048576;       // [4096][1024]
    unsigned short* w2T    = w1T + (size_t)4194304;          // [1024][4096]

    dim3 blk(256);
    const int MC = M * C;

    hipLaunchKernelGGL(cvt_bf16, dim3(MC / 1024), blk, 0, stream, expl, Ebf, MC);
    hipLaunchKernelGGL(cvt_bf16, dim3(MC / 1024), blk, 0, stream, x, Xbf, MC);
    hipLaunchKernelGGL(transpose_cvt, dim3(96, 32), blk, 0, stream, w_qkv, wqkvT, C, 3 * C);
    hipLaunchKernelGGL(transpose_cvt, dim3(32, 32), blk, 0, stream, w_proj, wprojT, C, C);
    hipLaunchKernelGGL(transpose_cvt, dim3(128, 32), blk, 0, stream, w1, w1T, C, F);
    hipLaunchKernelGGL(transpose_cvt, dim3(32, 128), blk, 0, stream, w2, w2T, F, C);

    // QK projection; V projection  [gemm97o, 4 waves/EU forced]
    hipLaunchKernelGGL((gemm97o<0,1,32>), dim3(64 * 16), blk, 0, stream, Ebf, wqkvT, (const float*)nullptr, (void*)QKbf, M, 2048, C, 2048);
    hipLaunchKernelGGL((gemm97o<0,1,32>), dim3(64 * 8), blk, 0, stream, Xbf, wqkvT + (size_t)2048 * 1024, (const float*)nullptr, (void*)Vbf, M, 1024, C, 1024);

    // drofe: bf16 QK -> rotated bf16 Q (scaled), K
    hipLaunchKernelGGL(drofe_bf, dim3(M * 512 / 256), blk, 0, stream, QKbf, Qbf, Kbf, fb, demo, N);

    // attention -> bf16 O
    hipLaunchKernelGGL(attn_mfma, dim3(B * H * (N / 64)), blk, 0, stream, Qbf, Kbf, Vbf, Obf, B, H, N);

    // output projection -> bf16 Pb
    hipLaunchKernelGGL((gemm97o<1,1,32>), dim3(64 * 8), blk, 0, stream, Obf, wprojT, b_proj, (void*)Pb, M, 1024, C, 1024);

    // residual + LN1 (f32 + bf16)
    hipLaunchKernelGGL(ln_res_kernel, dim3(M), blk, 0, stream, x, Pb, gamma1, ln1_w, ln1_b, X1, X1bf, C);

    // MLP: MLP1 [gemm97o BK=32, fast gelu], MLP2 [gemm97o BK=64, K=4096] -> bf16
    hipLaunchKernelGGL((gemm97o<2,1,32>), dim3(64 * 32), blk, 0, stream, X1bf, w1T, b1, (void*)Hid, M, F, C, F);
    hipLaunchKernelGGL((gemm97o<1,1,64>), dim3(64 * 8), blk, 0, stream, Hid, w2T, b2, (void*)H2, M, 1024, F, 1024);

    // residual + LN2 -> out
    hipLaunchKernelGGL(ln_res_kernel, dim3(M), blk, 0, stream, X1, H2, gamma2, ln2_w, ln2_b, out, (unsigned short*)nullptr, C);
}